// Round 3
// baseline (348.918 us; speedup 1.0000x reference)
//
#include <hip/hip_runtime.h>

// MegaNeRF fused MoE-MLP for MI355X (gfx950) — round 3: transposed dataflow.
// h^T = W^T @ feats^T per wave (16 points/wave), chained via in-register
// ds_bpermute exchange. No LDS, no barriers in the MLP kernel.
//
// Verified invariants kept from round 2: prep_pack layout (B-frag(W) ==
// A-frag(W^T)), route_compact, atomicAdd accumulation into zeroed d_out.

typedef __attribute__((ext_vector_type(8))) short   s16x8;
typedef __attribute__((ext_vector_type(4))) float   f32x4;

#define NPTS  65536
#define E_    8
#define DIN   90
#define H_    256
#define DOUT  4

// packed weight layout: [e][ct][ks][lane][j] bf16, 512 elems per (e,ct,ks)
#define W1P_ELEMS (E_*16*3*512)   // K padded to 96 -> 3 ksteps
#define W2P_ELEMS (E_*16*8*512)   // K=256 -> 8 ksteps
#define W3P_ELEMS (E_*1*8*512)    // N padded 4->16, K=256
#define W2P_OFF   (W1P_ELEMS)
#define W3P_OFF   (W1P_ELEMS + W2P_ELEMS)
#define WSP_TOTAL (W1P_ELEMS + W2P_ELEMS + W3P_ELEMS)
#define WSP_BYTES (WSP_TOTAL*2)          // 1,507,328 B
#define CNT_OFF   WSP_BYTES              // int[8]
#define LIST_OFF  (WSP_BYTES + 32)       // u16[E_*NPTS] = 1 MB

__device__ __forceinline__ unsigned short f2bf(float f) {
  union { float f; unsigned u; } v; v.f = f;
  unsigned u = v.u;
  u += 0x7fffu + ((u >> 16) & 1u);   // round-to-nearest-even
  return (unsigned short)(u >> 16);
}
__device__ __forceinline__ unsigned pkbf(float a, float b) {
  return (unsigned)f2bf(a) | ((unsigned)f2bf(b) << 16);
}

// ---------------- prep: pack W1/W2/W3 fp32 -> bf16 fragment layout ----------
// (unchanged — layout doubles as A-frag of W^T for the transposed dataflow)
__global__ void prep_pack(const float* __restrict__ W1,
                          const float* __restrict__ W2,
                          const float* __restrict__ W3,
                          unsigned short* __restrict__ P) {
  int idx = blockIdx.x * blockDim.x + threadIdx.x;
  if (idx >= WSP_TOTAL) return;
  float val;
  if (idx < W2P_OFF) {                       // W1: (e,90,256), K padded 96
    int f = idx;
    int j = f & 7, l = (f >> 3) & 63, t = f >> 9;
    int ks = t % 3; t /= 3;
    int ct = t & 15, e = t >> 4;
    int k = ks*32 + (l>>4)*8 + j;
    int n = ct*16 + (l & 15);
    val = (k < DIN) ? W1[((size_t)e*DIN + k)*H_ + n] : 0.f;
  } else if (idx < W3P_OFF) {                // W2: (e,256,256)
    int f = idx - W2P_OFF;
    int j = f & 7, l = (f >> 3) & 63, t = f >> 9;
    int ks = t & 7; t >>= 3;
    int ct = t & 15, e = t >> 4;
    int k = ks*32 + (l>>4)*8 + j;
    int n = ct*16 + (l & 15);
    val = W2[((size_t)e*H_ + k)*H_ + n];
  } else {                                   // W3: (e,256,4), N padded to 16
    int f = idx - W3P_OFF;
    int j = f & 7, l = (f >> 3) & 63, t = f >> 9;
    int ks = t & 7, e = t >> 3;
    int k = ks*32 + (l>>4)*8 + j;
    int n = l & 15;
    val = (n < DOUT) ? W3[((size_t)e*H_ + k)*DOUT + n] : 0.f;
  }
  P[idx] = f2bf(val);
}

// ---------------- routing + compaction into per-expert lists ----------------
__global__ __launch_bounds__(256)
void route_compact(const float* __restrict__ x,
                   const float* __restrict__ cen,
                   int* __restrict__ counts,
                   unsigned short* __restrict__ lists) {
  const int tid = threadIdx.x;
  const int gid = blockIdx.x * 256 + tid;
  __shared__ int lcnt[E_], lbase[E_];
  if (tid < E_) lcnt[tid] = 0;
  __syncthreads();

  const float* xr = x + (size_t)gid*93;
  float px = xr[0], py = xr[1], pz = xr[2];
  float d[E_], dmin = 1e30f;
  #pragma unroll
  for (int e = 0; e < E_; e++) {
    float dx = px - cen[e*3+0], dy = py - cen[e*3+1], dz = pz - cen[e*3+2];
    d[e] = sqrtf(dx*dx + dy*dy + dz*dz);
    dmin = fminf(dmin, d[e]);
  }
  int myoff[E_];
  int act = 0;
  #pragma unroll
  for (int e = 0; e < E_; e++) {
    bool a = !(d[e] > 2.0f*dmin);            // matches reference predicate
    if (a) { myoff[e] = atomicAdd(&lcnt[e], 1); act |= (1 << e); }
  }
  __syncthreads();
  if (tid < E_) lbase[tid] = atomicAdd(&counts[tid], lcnt[tid]);
  __syncthreads();
  #pragma unroll
  for (int e = 0; e < E_; e++)
    if ((act >> e) & 1)
      lists[e*NPTS + lbase[e] + myoff[e]] = (unsigned short)gid;
}

// ---------------- per-expert transposed MLP, 16 points per wave -------------
__global__ __launch_bounds__(256)
void expert_mlp(const float* __restrict__ x,
                const float* __restrict__ cen,
                const float* __restrict__ b1,
                const float* __restrict__ b2,
                const float* __restrict__ b3,
                const unsigned short* __restrict__ P,
                const int* __restrict__ counts,
                const unsigned short* __restrict__ lists,
                float* __restrict__ out) {
  const int e    = blockIdx.y;
  const int cnt  = counts[e];
  const int wid  = threadIdx.x >> 6;
  const int tile = blockIdx.x * 4 + wid;     // 16-point tile per wave
  if (tile * 16 >= cnt) return;              // wave-uniform exit

  const int lane = threadIdx.x & 63;
  const int lg   = lane >> 4;
  const int lr   = lane & 15;

  const int  slot  = tile*16 + lr;
  const bool valid = slot < cnt;
  const int  p     = valid ? (int)lists[e*NPTS + slot] : 0;
  const float* xr  = x + (size_t)p*93;

  // ---- routing weight for (p, e); every lane computes its column's point
  float wv;
  {
    float px = xr[0], py = xr[1], pz = xr[2];
    float d[E_], dmin = 1e30f;
    #pragma unroll
    for (int k = 0; k < E_; k++) {
      float dx = px - cen[k*3+0], dy = py - cen[k*3+1], dz = pz - cen[k*3+2];
      d[k] = sqrtf(dx*dx + dy*dy + dz*dz);
      dmin = fminf(dmin, d[k]);
    }
    float s = 0.f, mine = 0.f;
    #pragma unroll
    for (int k = 0; k < E_; k++) {
      float iv = (d[k] > 2.0f*dmin) ? 0.f : 1.0f/(d[k] + 1e-8f);
      s += iv;
      mine = (k == e) ? iv : mine;
    }
    wv = valid ? mine/s : 0.f;
  }

  // ================= G1: h1^T = W1^T @ feats^T, K=96 =======================
  f32x4 acc[16];
  #pragma unroll
  for (int ct = 0; ct < 16; ct++) acc[ct] = (f32x4){0.f,0.f,0.f,0.f};

  #pragma unroll
  for (int ks = 0; ks < 3; ks++) {
    // B-frag: feats[p(lr)][d], d = ks*32 + lg*8 + j  (zeros past DIN)
    int d0 = ks*32 + lg*8;
    float f[8];
    #pragma unroll
    for (int j = 0; j < 8; j++)
      f[j] = (d0 + j < DIN) ? xr[3 + d0 + j] : 0.f;
    union { unsigned u[4]; s16x8 v; } bb;
    #pragma unroll
    for (int q = 0; q < 4; q++) bb.u[q] = pkbf(f[2*q], f[2*q+1]);

    const unsigned short* Pk = P + (((e*16)*3 + ks) << 9) + lane*8;
    #pragma unroll
    for (int ct = 0; ct < 16; ct++) {
      s16x8 a = *(const s16x8*)(Pk + ((ct*3) << 9));
      acc[ct] = __builtin_amdgcn_mfma_f32_16x16x32_bf16(a, bb.v, acc[ct], 0,0,0);
    }
  }

  // bias + relu -> packed bf16 h1 (lane holds n = ct*16 + 4*lg + r, m = lr)
  unsigned h1[32];
  #pragma unroll
  for (int ct = 0; ct < 16; ct++) {
    const float4 bv = *(const float4*)&b1[e*H_ + ct*16 + lg*4];
    float v0 = fmaxf(acc[ct][0] + bv.x, 0.f);
    float v1 = fmaxf(acc[ct][1] + bv.y, 0.f);
    float v2 = fmaxf(acc[ct][2] + bv.z, 0.f);
    float v3 = fmaxf(acc[ct][3] + bv.w, 0.f);
    h1[2*ct]   = pkbf(v0, v1);
    h1[2*ct+1] = pkbf(v2, v3);
  }

  // cross-lg exchange constants: consumer (lg',lr) pulls from
  // src = 32*(lg'&1) + 16*(q>>1) + lr ; ct = 2ks + (lg'>>1)
  const int  addrA = (32*(lg & 1) + lr) * 4;
  const int  addrB = addrA + 64;
  const bool hi    = (lg >> 1) != 0;

  // ================= G2: h2^T = W2^T @ h1^T, K=256 =========================
  #pragma unroll
  for (int ct = 0; ct < 16; ct++) acc[ct] = (f32x4){0.f,0.f,0.f,0.f};

  #pragma unroll
  for (int ks = 0; ks < 8; ks++) {
    union { unsigned u[4]; s16x8 v; } bb;
    {
      unsigned a0 = (unsigned)__builtin_amdgcn_ds_bpermute(addrA, (int)h1[4*ks+0]);
      unsigned b0 = (unsigned)__builtin_amdgcn_ds_bpermute(addrA, (int)h1[4*ks+2]);
      unsigned a1 = (unsigned)__builtin_amdgcn_ds_bpermute(addrA, (int)h1[4*ks+1]);
      unsigned b1_ = (unsigned)__builtin_amdgcn_ds_bpermute(addrA, (int)h1[4*ks+3]);
      unsigned a2 = (unsigned)__builtin_amdgcn_ds_bpermute(addrB, (int)h1[4*ks+0]);
      unsigned b2_ = (unsigned)__builtin_amdgcn_ds_bpermute(addrB, (int)h1[4*ks+2]);
      unsigned a3 = (unsigned)__builtin_amdgcn_ds_bpermute(addrB, (int)h1[4*ks+1]);
      unsigned b3_ = (unsigned)__builtin_amdgcn_ds_bpermute(addrB, (int)h1[4*ks+3]);
      bb.u[0] = hi ? b0 : a0;
      bb.u[1] = hi ? b1_ : a1;
      bb.u[2] = hi ? b2_ : a2;
      bb.u[3] = hi ? b3_ : a3;
    }
    const unsigned short* Pk = P + W2P_OFF + (((e*16)*8 + ks) << 9) + lane*8;
    #pragma unroll
    for (int ct = 0; ct < 16; ct++) {
      s16x8 a = *(const s16x8*)(Pk + ((ct*8) << 9));
      acc[ct] = __builtin_amdgcn_mfma_f32_16x16x32_bf16(a, bb.v, acc[ct], 0,0,0);
    }
  }

  // bias + relu -> packed bf16 h2
  unsigned h2[32];
  #pragma unroll
  for (int ct = 0; ct < 16; ct++) {
    const float4 bv = *(const float4*)&b2[e*H_ + ct*16 + lg*4];
    float v0 = fmaxf(acc[ct][0] + bv.x, 0.f);
    float v1 = fmaxf(acc[ct][1] + bv.y, 0.f);
    float v2 = fmaxf(acc[ct][2] + bv.z, 0.f);
    float v3 = fmaxf(acc[ct][3] + bv.w, 0.f);
    h2[2*ct]   = pkbf(v0, v1);
    h2[2*ct+1] = pkbf(v2, v3);
  }

  // ================= G3: out^T = W3^T @ h2^T (rows padded to 16) ===========
  f32x4 acc3 = (f32x4){0.f,0.f,0.f,0.f};
  #pragma unroll
  for (int ks = 0; ks < 8; ks++) {
    union { unsigned u[4]; s16x8 v; } bb;
    {
      unsigned a0 = (unsigned)__builtin_amdgcn_ds_bpermute(addrA, (int)h2[4*ks+0]);
      unsigned b0 = (unsigned)__builtin_amdgcn_ds_bpermute(addrA, (int)h2[4*ks+2]);
      unsigned a1 = (unsigned)__builtin_amdgcn_ds_bpermute(addrA, (int)h2[4*ks+1]);
      unsigned b1_ = (unsigned)__builtin_amdgcn_ds_bpermute(addrA, (int)h2[4*ks+3]);
      unsigned a2 = (unsigned)__builtin_amdgcn_ds_bpermute(addrB, (int)h2[4*ks+0]);
      unsigned b2_ = (unsigned)__builtin_amdgcn_ds_bpermute(addrB, (int)h2[4*ks+2]);
      unsigned a3 = (unsigned)__builtin_amdgcn_ds_bpermute(addrB, (int)h2[4*ks+1]);
      unsigned b3_ = (unsigned)__builtin_amdgcn_ds_bpermute(addrB, (int)h2[4*ks+3]);
      bb.u[0] = hi ? b0 : a0;
      bb.u[1] = hi ? b1_ : a1;
      bb.u[2] = hi ? b2_ : a2;
      bb.u[3] = hi ? b3_ : a3;
    }
    s16x8 a = *(const s16x8*)(P + W3P_OFF + ((e*8 + ks) << 9) + lane*8);
    acc3 = __builtin_amdgcn_mfma_f32_16x16x32_bf16(a, bb.v, acc3, 0,0,0);
  }

  // lane (lg=0, lr) holds all DOUT outputs of point p(lr) in acc3[0..3]
  if (lg == 0 && valid && wv != 0.f) {
    #pragma unroll
    for (int r = 0; r < 4; r++)
      atomicAdd(&out[(size_t)p*DOUT + r], wv * (acc3[r] + b3[e*DOUT + r]));
  }
}

// ---------------- launcher --------------------------------------------------
extern "C" void kernel_launch(void* const* d_in, const int* in_sizes, int n_in,
                              void* d_out, int out_size, void* d_ws, size_t ws_size,
                              hipStream_t stream) {
  const float* x   = (const float*)d_in[0];
  const float* cen = (const float*)d_in[1];
  const float* W1  = (const float*)d_in[2];
  const float* b1  = (const float*)d_in[3];
  const float* W2  = (const float*)d_in[4];
  const float* b2  = (const float*)d_in[5];
  const float* W3  = (const float*)d_in[6];
  const float* b3  = (const float*)d_in[7];

  unsigned short* P     = (unsigned short*)d_ws;
  int*            cnts  = (int*)((char*)d_ws + CNT_OFF);
  unsigned short* lists = (unsigned short*)((char*)d_ws + LIST_OFF);
  float* out = (float*)d_out;

  hipMemsetAsync(cnts, 0, 32, stream);
  hipMemsetAsync(out, 0, (size_t)NPTS*DOUT*sizeof(float), stream);
  prep_pack<<<dim3((WSP_TOTAL + 255)/256), dim3(256), 0, stream>>>(W1, W2, W3, P);
  route_compact<<<dim3(NPTS/256), dim3(256), 0, stream>>>(x, cen, cnts, lists);
  expert_mlp<<<dim3(NPTS/64, E_), dim3(256), 0, stream>>>(x, cen, b1, b2, b3, P,
                                                          cnts, lists, out);
}

// Round 5
// 168.372 us; speedup vs baseline: 2.0723x; 2.0723x over previous
//
#include <hip/hip_runtime.h>

// MegaNeRF fused MoE-MLP for MI355X (gfx950) — round 5 (= round 4 + compile fix).
// Transposed dataflow with block-level weight reuse and vectorized LDS h-exchange.
//
// Per block: 64 points, 4 waves. Wave w owns n-slice ct in {4w..4w+3} of all
// GEMMs (computed as h^T = W^T @ feats^T), iterating 4 bt point-tiles -> each
// weight fragment loads once per block, 4x register reuse.
// h^T C-frag has 4 consecutive n per lane == k-contiguous for the next layer
// -> LDS h written as packed-bf16 pairs + 8B writes, read back as ds_read_b128.
// XOR swizzle (m&7)<<4 on both sides keeps LDS conflict-free.

typedef __attribute__((ext_vector_type(8))) short   s16x8;
typedef __attribute__((ext_vector_type(4))) float   f32x4;

#define NPTS  65536
#define E_    8
#define DIN   90
#define H_    256
#define DOUT  4

// packed weight layout: [e][ct][ks][lane][j] bf16, 512 elems per (e,ct,ks)
#define W1P_ELEMS (E_*16*3*512)   // K padded to 96 -> 3 ksteps
#define W2P_ELEMS (E_*16*8*512)   // K=256 -> 8 ksteps
#define W3P_ELEMS (E_*1*8*512)    // N padded 4->16, K=256
#define W2P_OFF   (W1P_ELEMS)
#define W3P_OFF   (W1P_ELEMS + W2P_ELEMS)
#define WSP_TOTAL (W1P_ELEMS + W2P_ELEMS + W3P_ELEMS)
#define WSP_BYTES (WSP_TOTAL*2)          // 1,507,328 B
#define CNT_OFF   WSP_BYTES              // int[8]
#define LIST_OFF  (WSP_BYTES + 32)       // u16[E_*NPTS] = 1 MB

__device__ __forceinline__ unsigned short f2bf(float f) {
  union { float f; unsigned u; } v; v.f = f;
  unsigned u = v.u;
  u += 0x7fffu + ((u >> 16) & 1u);   // round-to-nearest-even
  return (unsigned short)(u >> 16);
}
__device__ __forceinline__ unsigned pk2(float a, float b) {
  return (unsigned)f2bf(a) | ((unsigned)f2bf(b) << 16);
}

// ---------------- prep: pack W1/W2/W3 fp32 -> bf16 fragment layout ----------
__global__ void prep_pack(const float* __restrict__ W1,
                          const float* __restrict__ W2,
                          const float* __restrict__ W3,
                          unsigned short* __restrict__ P) {
  int idx = blockIdx.x * blockDim.x + threadIdx.x;
  if (idx >= WSP_TOTAL) return;
  float val;
  if (idx < W2P_OFF) {                       // W1: (e,90,256), K padded 96
    int f = idx;
    int j = f & 7, l = (f >> 3) & 63, t = f >> 9;
    int ks = t % 3; t /= 3;
    int ct = t & 15, e = t >> 4;
    int k = ks*32 + (l>>4)*8 + j;
    int n = ct*16 + (l & 15);
    val = (k < DIN) ? W1[((size_t)e*DIN + k)*H_ + n] : 0.f;
  } else if (idx < W3P_OFF) {                // W2: (e,256,256)
    int f = idx - W2P_OFF;
    int j = f & 7, l = (f >> 3) & 63, t = f >> 9;
    int ks = t & 7; t >>= 3;
    int ct = t & 15, e = t >> 4;
    int k = ks*32 + (l>>4)*8 + j;
    int n = ct*16 + (l & 15);
    val = W2[((size_t)e*H_ + k)*H_ + n];
  } else {                                   // W3: (e,256,4), N padded to 16
    int f = idx - W3P_OFF;
    int j = f & 7, l = (f >> 3) & 63, t = f >> 9;
    int ks = t & 7, e = t >> 3;
    int k = ks*32 + (l>>4)*8 + j;
    int n = l & 15;
    val = (n < DOUT) ? W3[((size_t)e*H_ + k)*DOUT + n] : 0.f;
  }
  P[idx] = f2bf(val);
}

// ---------------- routing + compaction into per-expert lists ----------------
__global__ __launch_bounds__(256)
void route_compact(const float* __restrict__ x,
                   const float* __restrict__ cen,
                   int* __restrict__ counts,
                   unsigned short* __restrict__ lists) {
  const int tid = threadIdx.x;
  const int gid = blockIdx.x * 256 + tid;
  __shared__ int lcnt[E_], lbase[E_];
  if (tid < E_) lcnt[tid] = 0;
  __syncthreads();

  const float* xr = x + (size_t)gid*93;
  float px = xr[0], py = xr[1], pz = xr[2];
  float d[E_], dmin = 1e30f;
  #pragma unroll
  for (int e = 0; e < E_; e++) {
    float dx = px - cen[e*3+0], dy = py - cen[e*3+1], dz = pz - cen[e*3+2];
    d[e] = sqrtf(dx*dx + dy*dy + dz*dz);
    dmin = fminf(dmin, d[e]);
  }
  int myoff[E_];
  int act = 0;
  #pragma unroll
  for (int e = 0; e < E_; e++) {
    bool a = !(d[e] > 2.0f*dmin);            // matches reference predicate
    if (a) { myoff[e] = atomicAdd(&lcnt[e], 1); act |= (1 << e); }
  }
  __syncthreads();
  if (tid < E_) lbase[tid] = atomicAdd(&counts[tid], lcnt[tid]);
  __syncthreads();
  #pragma unroll
  for (int e = 0; e < E_; e++)
    if ((act >> e) & 1)
      lists[e*NPTS + lbase[e] + myoff[e]] = (unsigned short)gid;
}

// ---------------- per-expert transposed MLP, 64 points per block ------------
#define FB_LD 104   // padded row stride (elems) for feats: conflict-free + 16B aligned

__global__ __launch_bounds__(256)
void expert_mlp(const float* __restrict__ x,
                const float* __restrict__ cen,
                const float* __restrict__ b1,
                const float* __restrict__ b2,
                const float* __restrict__ b3,
                const unsigned short* __restrict__ P,
                const int* __restrict__ counts,
                const unsigned short* __restrict__ lists,
                float* __restrict__ out) {
  const int e   = blockIdx.y;
  const int cnt = counts[e];
  const int t   = blockIdx.x;
  if (t*64 >= cnt) return;

  __shared__ __attribute__((aligned(16))) unsigned short sFb[64*FB_LD]; // 13.3KB
  __shared__ __attribute__((aligned(16))) unsigned short sH[64*256];    // 32KB
  __shared__ float          sWv[64];
  __shared__ unsigned short sIdx[64];

  const int tid  = threadIdx.x;
  const int wid  = tid >> 6;
  const int lane = tid & 63;
  const int lg   = lane >> 4;
  const int lr   = lane & 15;

  // ---- routing weights (64 threads) -- in parallel with feats staging below
  if (tid < 64) {
    int slot = t*64 + tid;
    int p = (slot < cnt) ? (int)lists[e*NPTS + slot] : 0;
    sIdx[tid] = (unsigned short)p;
    const float* xr = x + (size_t)p*93;
    float px = xr[0], py = xr[1], pz = xr[2];
    float d[E_], dmin = 1e30f;
    #pragma unroll
    for (int k = 0; k < E_; k++) {
      float dx = px - cen[k*3+0], dy = py - cen[k*3+1], dz = pz - cen[k*3+2];
      d[k] = sqrtf(dx*dx + dy*dy + dz*dz);
      dmin = fminf(dmin, d[k]);
    }
    float s = 0.f, mine = 0.f;
    #pragma unroll
    for (int k = 0; k < E_; k++) {
      float iv = (d[k] > 2.0f*dmin) ? 0.f : 1.0f/(d[k] + 1e-8f);
      s += iv;
      mine = (k == e) ? iv : mine;
    }
    sWv[tid] = (slot < cnt) ? mine/s : 0.f;
  }

  // ---- stage feats -> bf16 LDS [64][FB_LD], cols 90..95 zero (own p lookup)
  #pragma unroll
  for (int it = 0; it < 12; it++) {
    int i = tid + 256*it;              // 0..3071
    int r = i / 48, c = i - r*48;      // point r, elem pair c (dins 2c,2c+1)
    int slot = t*64 + r;
    int p = (slot < cnt) ? (int)lists[e*NPTS + slot] : 0;
    const float* xr = x + (size_t)p*93 + 3;
    float v0 = (2*c   < DIN) ? xr[2*c]   : 0.f;
    float v1 = (2*c+1 < DIN) ? xr[2*c+1] : 0.f;
    ((unsigned*)sFb)[r*(FB_LD/2) + c] = pk2(v0, v1);
  }
  __syncthreads();

  f32x4 acc[4][4];   // [nt][bt]
  // ========== G1^T: h1^T = W1^T @ feats^T, K=96 ==========
  #pragma unroll
  for (int nt = 0; nt < 4; nt++)
    #pragma unroll
    for (int bt = 0; bt < 4; bt++) acc[nt][bt] = (f32x4){0.f,0.f,0.f,0.f};

  #pragma unroll
  for (int ks = 0; ks < 3; ks++) {
    s16x8 bfr[4];
    #pragma unroll
    for (int bt = 0; bt < 4; bt++)
      bfr[bt] = *(const s16x8*)&sFb[(16*bt + lr)*FB_LD + 32*ks + 8*lg];
    const unsigned short* Pk = P + (((e*16 + wid*4)*3 + ks) << 9) + lane*8;
    #pragma unroll
    for (int nt = 0; nt < 4; nt++) {
      s16x8 a = *(const s16x8*)(Pk + ((nt*3) << 9));
      #pragma unroll
      for (int bt = 0; bt < 4; bt++)
        acc[nt][bt] = __builtin_amdgcn_mfma_f32_16x16x32_bf16(a, bfr[bt], acc[nt][bt], 0,0,0);
    }
  }

  // epilogue 1: bias+relu, pack, 8B write to sH (m-major, k-contig, XOR swz)
  #pragma unroll
  for (int nt = 0; nt < 4; nt++) {
    int ct = wid*4 + nt;
    float4 bv = *(const float4*)&b1[e*H_ + ct*16 + lg*4];
    #pragma unroll
    for (int bt = 0; bt < 4; bt++) {
      float v0 = fmaxf(acc[nt][bt][0] + bv.x, 0.f);
      float v1 = fmaxf(acc[nt][bt][1] + bv.y, 0.f);
      float v2 = fmaxf(acc[nt][bt][2] + bv.z, 0.f);
      float v3 = fmaxf(acc[nt][bt][3] + bv.w, 0.f);
      int m   = 16*bt + lr;
      int byt = (32*ct + 8*lg) ^ ((m & 7) << 4);
      uint2 pkd; pkd.x = pk2(v0, v1); pkd.y = pk2(v2, v3);
      *(uint2*)((char*)sH + m*512 + byt) = pkd;
    }
  }
  __syncthreads();

  // ========== G2^T: h2^T = W2^T @ h1^T, K=256 ==========
  #pragma unroll
  for (int nt = 0; nt < 4; nt++)
    #pragma unroll
    for (int bt = 0; bt < 4; bt++) acc[nt][bt] = (f32x4){0.f,0.f,0.f,0.f};

  #pragma unroll
  for (int ks = 0; ks < 8; ks++) {
    s16x8 bfr[4];
    #pragma unroll
    for (int bt = 0; bt < 4; bt++) {
      int m = 16*bt + lr;
      int byt = (64*ks + 16*lg) ^ ((m & 7) << 4);
      bfr[bt] = *(const s16x8*)((const char*)sH + m*512 + byt);
    }
    const unsigned short* Pk = P + W2P_OFF + (((e*16 + wid*4)*8 + ks) << 9) + lane*8;
    #pragma unroll
    for (int nt = 0; nt < 4; nt++) {
      s16x8 a = *(const s16x8*)(Pk + ((nt*8) << 9));
      #pragma unroll
      for (int bt = 0; bt < 4; bt++)
        acc[nt][bt] = __builtin_amdgcn_mfma_f32_16x16x32_bf16(a, bfr[bt], acc[nt][bt], 0,0,0);
    }
  }
  __syncthreads();   // all G2 reads of h1 complete

  // epilogue 2: bias+relu -> sH (h2)
  #pragma unroll
  for (int nt = 0; nt < 4; nt++) {
    int ct = wid*4 + nt;
    float4 bv = *(const float4*)&b2[e*H_ + ct*16 + lg*4];
    #pragma unroll
    for (int bt = 0; bt < 4; bt++) {
      float v0 = fmaxf(acc[nt][bt][0] + bv.x, 0.f);
      float v1 = fmaxf(acc[nt][bt][1] + bv.y, 0.f);
      float v2 = fmaxf(acc[nt][bt][2] + bv.z, 0.f);
      float v3 = fmaxf(acc[nt][bt][3] + bv.w, 0.f);
      int m   = 16*bt + lr;
      int byt = (32*ct + 8*lg) ^ ((m & 7) << 4);
      uint2 pkd; pkd.x = pk2(v0, v1); pkd.y = pk2(v2, v3);
      *(uint2*)((char*)sH + m*512 + byt) = pkd;
    }
  }
  __syncthreads();

  // ========== G3^T: out^T = W3^T @ h2^T (n3 padded to 16), wave w: bt=w =====
  f32x4 acc3 = (f32x4){0.f,0.f,0.f,0.f};
  #pragma unroll
  for (int ks = 0; ks < 8; ks++) {
    int m = 16*wid + lr;
    int byt = (64*ks + 16*lg) ^ ((m & 7) << 4);
    s16x8 bb = *(const s16x8*)((const char*)sH + m*512 + byt);
    s16x8 a  = *(const s16x8*)(P + W3P_OFF + ((e*8 + ks) << 9) + lane*8);
    acc3 = __builtin_amdgcn_mfma_f32_16x16x32_bf16(a, bb, acc3, 0,0,0);
  }

  // lane (lg=0, lr): rows n3=0..3 of point m=16*wid+lr
  if (lg == 0) {
    int sl = 16*wid + lr;
    float wv = sWv[sl];
    if (wv != 0.f) {
      int p = sIdx[sl];
      #pragma unroll
      for (int r = 0; r < 4; r++)
        atomicAdd(&out[(size_t)p*DOUT + r], wv * (acc3[r] + b3[e*DOUT + r]));
    }
  }
}

// ---------------- launcher --------------------------------------------------
extern "C" void kernel_launch(void* const* d_in, const int* in_sizes, int n_in,
                              void* d_out, int out_size, void* d_ws, size_t ws_size,
                              hipStream_t stream) {
  const float* x   = (const float*)d_in[0];
  const float* cen = (const float*)d_in[1];
  const float* W1  = (const float*)d_in[2];
  const float* b1  = (const float*)d_in[3];
  const float* W2  = (const float*)d_in[4];
  const float* b2  = (const float*)d_in[5];
  const float* W3  = (const float*)d_in[6];
  const float* b3  = (const float*)d_in[7];

  unsigned short* P     = (unsigned short*)d_ws;
  int*            cnts  = (int*)((char*)d_ws + CNT_OFF);
  unsigned short* lists = (unsigned short*)((char*)d_ws + LIST_OFF);
  float* out = (float*)d_out;

  (void)hipMemsetAsync(cnts, 0, 32, stream);
  (void)hipMemsetAsync(out, 0, (size_t)NPTS*DOUT*sizeof(float), stream);
  prep_pack<<<dim3((WSP_TOTAL + 255)/256), dim3(256), 0, stream>>>(W1, W2, W3, P);
  route_compact<<<dim3(NPTS/256), dim3(256), 0, stream>>>(x, cen, cnts, lists);
  expert_mlp<<<dim3(NPTS/64, E_), dim3(256), 0, stream>>>(x, cen, b1, b2, b3, P,
                                                          cnts, lists, out);
}

// Round 6
// 135.569 us; speedup vs baseline: 2.5737x; 1.2420x over previous
//
#include <hip/hip_runtime.h>

// MegaNeRF fused MoE-MLP for MI355X (gfx950) — round 6: occupancy + critical path.
// vs round 5: feats read direct from global in G1 (no sFb staging, no division
// loop, one less barrier), LDS = sH only (33KB -> 4 blocks/CU), launch_bounds
// (256,4). G2/G3/epilogues byte-identical to the round-5 verified code.

typedef __attribute__((ext_vector_type(8))) short   s16x8;
typedef __attribute__((ext_vector_type(4))) float   f32x4;

#define NPTS  65536
#define E_    8
#define DIN   90
#define H_    256
#define DOUT  4

// packed weight layout: [e][ct][ks][lane][j] bf16, 512 elems per (e,ct,ks)
#define W1P_ELEMS (E_*16*3*512)   // K padded to 96 -> 3 ksteps
#define W2P_ELEMS (E_*16*8*512)   // K=256 -> 8 ksteps
#define W3P_ELEMS (E_*1*8*512)    // N padded 4->16, K=256
#define W2P_OFF   (W1P_ELEMS)
#define W3P_OFF   (W1P_ELEMS + W2P_ELEMS)
#define WSP_TOTAL (W1P_ELEMS + W2P_ELEMS + W3P_ELEMS)
#define WSP_BYTES (WSP_TOTAL*2)          // 1,507,328 B
#define CNT_OFF   WSP_BYTES              // int[8]
#define LIST_OFF  (WSP_BYTES + 32)       // u16[E_*NPTS] = 1 MB

__device__ __forceinline__ unsigned short f2bf(float f) {
  union { float f; unsigned u; } v; v.f = f;
  unsigned u = v.u;
  u += 0x7fffu + ((u >> 16) & 1u);   // round-to-nearest-even
  return (unsigned short)(u >> 16);
}
__device__ __forceinline__ unsigned pk2(float a, float b) {
  return (unsigned)f2bf(a) | ((unsigned)f2bf(b) << 16);
}

// ---------------- prep: pack W1/W2/W3 fp32 -> bf16 fragment layout ----------
__global__ void prep_pack(const float* __restrict__ W1,
                          const float* __restrict__ W2,
                          const float* __restrict__ W3,
                          unsigned short* __restrict__ P) {
  int idx = blockIdx.x * blockDim.x + threadIdx.x;
  if (idx >= WSP_TOTAL) return;
  float val;
  if (idx < W2P_OFF) {                       // W1: (e,90,256), K padded 96
    int f = idx;
    int j = f & 7, l = (f >> 3) & 63, t = f >> 9;
    int ks = t % 3; t /= 3;
    int ct = t & 15, e = t >> 4;
    int k = ks*32 + (l>>4)*8 + j;
    int n = ct*16 + (l & 15);
    val = (k < DIN) ? W1[((size_t)e*DIN + k)*H_ + n] : 0.f;
  } else if (idx < W3P_OFF) {                // W2: (e,256,256)
    int f = idx - W2P_OFF;
    int j = f & 7, l = (f >> 3) & 63, t = f >> 9;
    int ks = t & 7; t >>= 3;
    int ct = t & 15, e = t >> 4;
    int k = ks*32 + (l>>4)*8 + j;
    int n = ct*16 + (l & 15);
    val = W2[((size_t)e*H_ + k)*H_ + n];
  } else {                                   // W3: (e,256,4), N padded to 16
    int f = idx - W3P_OFF;
    int j = f & 7, l = (f >> 3) & 63, t = f >> 9;
    int ks = t & 7, e = t >> 3;
    int k = ks*32 + (l>>4)*8 + j;
    int n = l & 15;
    val = (n < DOUT) ? W3[((size_t)e*H_ + k)*DOUT + n] : 0.f;
  }
  P[idx] = f2bf(val);
}

// ---------------- routing + compaction into per-expert lists ----------------
__global__ __launch_bounds__(256)
void route_compact(const float* __restrict__ x,
                   const float* __restrict__ cen,
                   int* __restrict__ counts,
                   unsigned short* __restrict__ lists) {
  const int tid = threadIdx.x;
  const int gid = blockIdx.x * 256 + tid;
  __shared__ int lcnt[E_], lbase[E_];
  if (tid < E_) lcnt[tid] = 0;
  __syncthreads();

  const float* xr = x + (size_t)gid*93;
  float px = xr[0], py = xr[1], pz = xr[2];
  float d[E_], dmin = 1e30f;
  #pragma unroll
  for (int e = 0; e < E_; e++) {
    float dx = px - cen[e*3+0], dy = py - cen[e*3+1], dz = pz - cen[e*3+2];
    d[e] = sqrtf(dx*dx + dy*dy + dz*dz);
    dmin = fminf(dmin, d[e]);
  }
  int myoff[E_];
  int act = 0;
  #pragma unroll
  for (int e = 0; e < E_; e++) {
    bool a = !(d[e] > 2.0f*dmin);            // matches reference predicate
    if (a) { myoff[e] = atomicAdd(&lcnt[e], 1); act |= (1 << e); }
  }
  __syncthreads();
  if (tid < E_) lbase[tid] = atomicAdd(&counts[tid], lcnt[tid]);
  __syncthreads();
  #pragma unroll
  for (int e = 0; e < E_; e++)
    if ((act >> e) & 1)
      lists[e*NPTS + lbase[e] + myoff[e]] = (unsigned short)gid;
}

// ---------------- per-expert transposed MLP, 64 points per block ------------
__global__ __launch_bounds__(256, 4)
void expert_mlp(const float* __restrict__ x,
                const float* __restrict__ cen,
                const float* __restrict__ b1,
                const float* __restrict__ b2,
                const float* __restrict__ b3,
                const unsigned short* __restrict__ P,
                const int* __restrict__ counts,
                const unsigned short* __restrict__ lists,
                float* __restrict__ out) {
  const int e   = blockIdx.y;
  const int cnt = counts[e];
  const int t   = blockIdx.x;
  if (t*64 >= cnt) return;

  __shared__ __attribute__((aligned(16))) unsigned short sH[64*256];  // 32KB
  __shared__ float sWv[64];

  const int tid  = threadIdx.x;
  const int wid  = tid >> 6;
  const int lane = tid & 63;
  const int lg   = lane >> 4;
  const int lr   = lane & 15;

  // ---- routing weights (wave 0) — read at G3 (two barriers downstream)
  if (tid < 64) {
    int slot = t*64 + tid;
    int p = (slot < cnt) ? (int)lists[e*NPTS + slot] : 0;
    const float* xr = x + (size_t)p*93;
    float px = xr[0], py = xr[1], pz = xr[2];
    float d[E_], dmin = 1e30f;
    #pragma unroll
    for (int k = 0; k < E_; k++) {
      float dx = px - cen[k*3+0], dy = py - cen[k*3+1], dz = pz - cen[k*3+2];
      d[k] = sqrtf(dx*dx + dy*dy + dz*dz);
      dmin = fminf(dmin, d[k]);
    }
    float s = 0.f, mine = 0.f;
    #pragma unroll
    for (int k = 0; k < E_; k++) {
      float iv = (d[k] > 2.0f*dmin) ? 0.f : 1.0f/(d[k] + 1e-8f);
      s += iv;
      mine = (k == e) ? iv : mine;
    }
    sWv[tid] = (slot < cnt) ? mine/s : 0.f;
  }

  // ---- per-bt point indices (lane lr owns point 16*bt+lr)
  int pA[4];
  #pragma unroll
  for (int bt = 0; bt < 4; bt++) {
    int slot = t*64 + 16*bt + lr;
    pA[bt] = (slot < cnt) ? (int)lists[e*NPTS + slot] : 0;
  }

  f32x4 acc[4][4];   // [nt][bt]
  // ========== G1^T: h1^T = W1^T @ feats^T, K=96 (feats direct from global) ==
  #pragma unroll
  for (int nt = 0; nt < 4; nt++)
    #pragma unroll
    for (int bt = 0; bt < 4; bt++) acc[nt][bt] = (f32x4){0.f,0.f,0.f,0.f};

  #pragma unroll
  for (int ks = 0; ks < 3; ks++) {
    s16x8 bfr[4];
    #pragma unroll
    for (int bt = 0; bt < 4; bt++) {
      const float* xr = x + (size_t)pA[bt]*93 + 3;
      int d0 = 32*ks + 8*lg;
      float f[8];
      #pragma unroll
      for (int j = 0; j < 8; j++)
        f[j] = (d0 + j < DIN) ? xr[d0 + j] : 0.f;
      union { unsigned u[4]; s16x8 v; } bb;
      #pragma unroll
      for (int q = 0; q < 4; q++) bb.u[q] = pk2(f[2*q], f[2*q+1]);
      bfr[bt] = bb.v;
    }
    const unsigned short* Pk = P + (((e*16 + wid*4)*3 + ks) << 9) + lane*8;
    #pragma unroll
    for (int nt = 0; nt < 4; nt++) {
      s16x8 a = *(const s16x8*)(Pk + ((nt*3) << 9));
      #pragma unroll
      for (int bt = 0; bt < 4; bt++)
        acc[nt][bt] = __builtin_amdgcn_mfma_f32_16x16x32_bf16(a, bfr[bt], acc[nt][bt], 0,0,0);
    }
  }

  // epilogue 1: bias+relu, pack, 8B write to sH (m-major, k-contig, XOR swz)
  #pragma unroll
  for (int nt = 0; nt < 4; nt++) {
    int ct = wid*4 + nt;
    float4 bv = *(const float4*)&b1[e*H_ + ct*16 + lg*4];
    #pragma unroll
    for (int bt = 0; bt < 4; bt++) {
      float v0 = fmaxf(acc[nt][bt][0] + bv.x, 0.f);
      float v1 = fmaxf(acc[nt][bt][1] + bv.y, 0.f);
      float v2 = fmaxf(acc[nt][bt][2] + bv.z, 0.f);
      float v3 = fmaxf(acc[nt][bt][3] + bv.w, 0.f);
      int m   = 16*bt + lr;
      int byt = (32*ct + 8*lg) ^ ((m & 7) << 4);
      uint2 pkd; pkd.x = pk2(v0, v1); pkd.y = pk2(v2, v3);
      *(uint2*)((char*)sH + m*512 + byt) = pkd;
    }
  }
  __syncthreads();

  // ========== G2^T: h2^T = W2^T @ h1^T, K=256 ==========
  #pragma unroll
  for (int nt = 0; nt < 4; nt++)
    #pragma unroll
    for (int bt = 0; bt < 4; bt++) acc[nt][bt] = (f32x4){0.f,0.f,0.f,0.f};

  #pragma unroll
  for (int ks = 0; ks < 8; ks++) {
    s16x8 bfr[4];
    #pragma unroll
    for (int bt = 0; bt < 4; bt++) {
      int m = 16*bt + lr;
      int byt = (64*ks + 16*lg) ^ ((m & 7) << 4);
      bfr[bt] = *(const s16x8*)((const char*)sH + m*512 + byt);
    }
    const unsigned short* Pk = P + W2P_OFF + (((e*16 + wid*4)*8 + ks) << 9) + lane*8;
    #pragma unroll
    for (int nt = 0; nt < 4; nt++) {
      s16x8 a = *(const s16x8*)(Pk + ((nt*8) << 9));
      #pragma unroll
      for (int bt = 0; bt < 4; bt++)
        acc[nt][bt] = __builtin_amdgcn_mfma_f32_16x16x32_bf16(a, bfr[bt], acc[nt][bt], 0,0,0);
    }
  }
  __syncthreads();   // all G2 reads of h1 complete

  // epilogue 2: bias+relu -> sH (h2)
  #pragma unroll
  for (int nt = 0; nt < 4; nt++) {
    int ct = wid*4 + nt;
    float4 bv = *(const float4*)&b2[e*H_ + ct*16 + lg*4];
    #pragma unroll
    for (int bt = 0; bt < 4; bt++) {
      float v0 = fmaxf(acc[nt][bt][0] + bv.x, 0.f);
      float v1 = fmaxf(acc[nt][bt][1] + bv.y, 0.f);
      float v2 = fmaxf(acc[nt][bt][2] + bv.z, 0.f);
      float v3 = fmaxf(acc[nt][bt][3] + bv.w, 0.f);
      int m   = 16*bt + lr;
      int byt = (32*ct + 8*lg) ^ ((m & 7) << 4);
      uint2 pkd; pkd.x = pk2(v0, v1); pkd.y = pk2(v2, v3);
      *(uint2*)((char*)sH + m*512 + byt) = pkd;
    }
  }
  __syncthreads();

  // ========== G3^T: out^T = W3^T @ h2^T (n3 padded to 16), wave w: bt=w =====
  f32x4 acc3 = (f32x4){0.f,0.f,0.f,0.f};
  #pragma unroll
  for (int ks = 0; ks < 8; ks++) {
    int m = 16*wid + lr;
    int byt = (64*ks + 16*lg) ^ ((m & 7) << 4);
    s16x8 bb = *(const s16x8*)((const char*)sH + m*512 + byt);
    s16x8 a  = *(const s16x8*)(P + W3P_OFF + ((e*8 + ks) << 9) + lane*8);
    acc3 = __builtin_amdgcn_mfma_f32_16x16x32_bf16(a, bb, acc3, 0,0,0);
  }

  // lane (lg=0, lr): rows n3=0..3 of point m=16*wid+lr  (pA[wid] is its index)
  if (lg == 0) {
    float wv = sWv[16*wid + lr];
    if (wv != 0.f) {
      int p = pA[wid];
      #pragma unroll
      for (int r = 0; r < 4; r++)
        atomicAdd(&out[(size_t)p*DOUT + r], wv * (acc3[r] + b3[e*DOUT + r]));
    }
  }
}

// ---------------- launcher --------------------------------------------------
extern "C" void kernel_launch(void* const* d_in, const int* in_sizes, int n_in,
                              void* d_out, int out_size, void* d_ws, size_t ws_size,
                              hipStream_t stream) {
  const float* x   = (const float*)d_in[0];
  const float* cen = (const float*)d_in[1];
  const float* W1  = (const float*)d_in[2];
  const float* b1  = (const float*)d_in[3];
  const float* W2  = (const float*)d_in[4];
  const float* b2  = (const float*)d_in[5];
  const float* W3  = (const float*)d_in[6];
  const float* b3  = (const float*)d_in[7];

  unsigned short* P     = (unsigned short*)d_ws;
  int*            cnts  = (int*)((char*)d_ws + CNT_OFF);
  unsigned short* lists = (unsigned short*)((char*)d_ws + LIST_OFF);
  float* out = (float*)d_out;

  (void)hipMemsetAsync(cnts, 0, 32, stream);
  (void)hipMemsetAsync(out, 0, (size_t)NPTS*DOUT*sizeof(float), stream);
  prep_pack<<<dim3((WSP_TOTAL + 255)/256), dim3(256), 0, stream>>>(W1, W2, W3, P);
  route_compact<<<dim3(NPTS/256), dim3(256), 0, stream>>>(x, cen, cnts, lists);
  expert_mlp<<<dim3(NPTS/64, E_), dim3(256), 0, stream>>>(x, cen, b1, b2, b3, P,
                                                          cnts, lists, out);
}

// Round 7
// 123.382 us; speedup vs baseline: 2.8280x; 1.0988x over previous
//
#include <hip/hip_runtime.h>

// MegaNeRF fused MoE-MLP for MI355X (gfx950) — round 7.
// vs round 6: (1) feats pre-packed to bf16 xb[N][96] -> G1 B-frag is one
// aligned 16B load (was 96 scattered scalar loads/wave); (2) explicit
// double-buffer of the long-latency operand stream in G1/G2 k-loops.
// G2/G3/epilogues and all layouts identical to the passing round-6 kernel.

typedef __attribute__((ext_vector_type(8))) short   s16x8;
typedef __attribute__((ext_vector_type(4))) float   f32x4;

#define NPTS  65536
#define E_    8
#define DIN   90
#define H_    256
#define DOUT  4

// packed weight layout: [e][ct][ks][lane][j] bf16, 512 elems per (e,ct,ks)
#define W1P_ELEMS (E_*16*3*512)   // K padded to 96 -> 3 ksteps
#define W2P_ELEMS (E_*16*8*512)   // K=256 -> 8 ksteps
#define W3P_ELEMS (E_*1*8*512)    // N padded 4->16, K=256
#define W2P_OFF   (W1P_ELEMS)
#define W3P_OFF   (W1P_ELEMS + W2P_ELEMS)
#define WSP_TOTAL (W1P_ELEMS + W2P_ELEMS + W3P_ELEMS)
#define WSP_BYTES (WSP_TOTAL*2)              // 1,507,328 B
#define CNT_OFF   WSP_BYTES                  // int[8]
#define LIST_OFF  (WSP_BYTES + 32)           // u16[E_*NPTS] = 1 MB
#define XB_OFF    (LIST_OFF + E_*NPTS*2)     // u16[NPTS*96] = 12.6 MB
// total ws usage ~15.2 MB

__device__ __forceinline__ unsigned short f2bf(float f) {
  union { float f; unsigned u; } v; v.f = f;
  unsigned u = v.u;
  u += 0x7fffu + ((u >> 16) & 1u);   // round-to-nearest-even
  return (unsigned short)(u >> 16);
}
__device__ __forceinline__ unsigned pk2(float a, float b) {
  return (unsigned)f2bf(a) | ((unsigned)f2bf(b) << 16);
}

// ---------------- prep: pack W1/W2/W3 fp32 -> bf16 fragment layout ----------
__global__ void prep_pack(const float* __restrict__ W1,
                          const float* __restrict__ W2,
                          const float* __restrict__ W3,
                          unsigned short* __restrict__ P) {
  int idx = blockIdx.x * blockDim.x + threadIdx.x;
  if (idx >= WSP_TOTAL) return;
  float val;
  if (idx < W2P_OFF) {                       // W1: (e,90,256), K padded 96
    int f = idx;
    int j = f & 7, l = (f >> 3) & 63, t = f >> 9;
    int ks = t % 3; t /= 3;
    int ct = t & 15, e = t >> 4;
    int k = ks*32 + (l>>4)*8 + j;
    int n = ct*16 + (l & 15);
    val = (k < DIN) ? W1[((size_t)e*DIN + k)*H_ + n] : 0.f;
  } else if (idx < W3P_OFF) {                // W2: (e,256,256)
    int f = idx - W2P_OFF;
    int j = f & 7, l = (f >> 3) & 63, t = f >> 9;
    int ks = t & 7; t >>= 3;
    int ct = t & 15, e = t >> 4;
    int k = ks*32 + (l>>4)*8 + j;
    int n = ct*16 + (l & 15);
    val = W2[((size_t)e*H_ + k)*H_ + n];
  } else {                                   // W3: (e,256,4), N padded to 16
    int f = idx - W3P_OFF;
    int j = f & 7, l = (f >> 3) & 63, t = f >> 9;
    int ks = t & 7, e = t >> 3;
    int k = ks*32 + (l>>4)*8 + j;
    int n = l & 15;
    val = (n < DOUT) ? W3[((size_t)e*H_ + k)*DOUT + n] : 0.f;
  }
  P[idx] = f2bf(val);
}

// ---------------- prep: pack feats fp32 -> bf16 xb[N][96] -------------------
__global__ __launch_bounds__(256)
void x_pack(const float* __restrict__ x, unsigned* __restrict__ xb32) {
  int i = blockIdx.x * blockDim.x + threadIdx.x;   // one u32 (2 bf16) each
  if (i >= NPTS*48) return;
  int n = i / 48, c = i - n*48;                    // feat pair c -> dims 2c,2c+1
  const float* xr = x + (size_t)n*93 + 3;
  float v0 = (2*c   < DIN) ? xr[2*c]   : 0.f;
  float v1 = (2*c+1 < DIN) ? xr[2*c+1] : 0.f;
  xb32[(size_t)n*48 + c] = pk2(v0, v1);
}

// ---------------- routing + compaction into per-expert lists ----------------
__global__ __launch_bounds__(256)
void route_compact(const float* __restrict__ x,
                   const float* __restrict__ cen,
                   int* __restrict__ counts,
                   unsigned short* __restrict__ lists) {
  const int tid = threadIdx.x;
  const int gid = blockIdx.x * 256 + tid;
  __shared__ int lcnt[E_], lbase[E_];
  if (tid < E_) lcnt[tid] = 0;
  __syncthreads();

  const float* xr = x + (size_t)gid*93;
  float px = xr[0], py = xr[1], pz = xr[2];
  float d[E_], dmin = 1e30f;
  #pragma unroll
  for (int e = 0; e < E_; e++) {
    float dx = px - cen[e*3+0], dy = py - cen[e*3+1], dz = pz - cen[e*3+2];
    d[e] = sqrtf(dx*dx + dy*dy + dz*dz);
    dmin = fminf(dmin, d[e]);
  }
  int myoff[E_];
  int act = 0;
  #pragma unroll
  for (int e = 0; e < E_; e++) {
    bool a = !(d[e] > 2.0f*dmin);            // matches reference predicate
    if (a) { myoff[e] = atomicAdd(&lcnt[e], 1); act |= (1 << e); }
  }
  __syncthreads();
  if (tid < E_) lbase[tid] = atomicAdd(&counts[tid], lcnt[tid]);
  __syncthreads();
  #pragma unroll
  for (int e = 0; e < E_; e++)
    if ((act >> e) & 1)
      lists[e*NPTS + lbase[e] + myoff[e]] = (unsigned short)gid;
}

// ---------------- per-expert transposed MLP, 64 points per block ------------
__global__ __launch_bounds__(256, 4)
void expert_mlp(const float* __restrict__ x,
                const float* __restrict__ cen,
                const float* __restrict__ b1,
                const float* __restrict__ b2,
                const float* __restrict__ b3,
                const unsigned short* __restrict__ P,
                const unsigned short* __restrict__ XB,
                const int* __restrict__ counts,
                const unsigned short* __restrict__ lists,
                float* __restrict__ out) {
  const int e   = blockIdx.y;
  const int cnt = counts[e];
  const int t   = blockIdx.x;
  if (t*64 >= cnt) return;

  __shared__ __attribute__((aligned(16))) unsigned short sH[64*256];  // 32KB
  __shared__ float sWv[64];

  const int tid  = threadIdx.x;
  const int wid  = tid >> 6;
  const int lane = tid & 63;
  const int lg   = lane >> 4;
  const int lr   = lane & 15;

  // ---- routing weights (wave 0) — read at G3 (two barriers downstream)
  if (tid < 64) {
    int slot = t*64 + tid;
    int p = (slot < cnt) ? (int)lists[e*NPTS + slot] : 0;
    const float* xr = x + (size_t)p*93;
    float px = xr[0], py = xr[1], pz = xr[2];
    float d[E_], dmin = 1e30f;
    #pragma unroll
    for (int k = 0; k < E_; k++) {
      float dx = px - cen[k*3+0], dy = py - cen[k*3+1], dz = pz - cen[k*3+2];
      d[k] = sqrtf(dx*dx + dy*dy + dz*dz);
      dmin = fminf(dmin, d[k]);
    }
    float s = 0.f, mine = 0.f;
    #pragma unroll
    for (int k = 0; k < E_; k++) {
      float iv = (d[k] > 2.0f*dmin) ? 0.f : 1.0f/(d[k] + 1e-8f);
      s += iv;
      mine = (k == e) ? iv : mine;
    }
    sWv[tid] = (slot < cnt) ? mine/s : 0.f;
  }

  // ---- per-bt point indices (lane lr owns point 16*bt+lr)
  int pA[4];
  #pragma unroll
  for (int bt = 0; bt < 4; bt++) {
    int slot = t*64 + 16*bt + lr;
    pA[bt] = (slot < cnt) ? (int)lists[e*NPTS + slot] : 0;
  }

  f32x4 acc[4][4];   // [nt][bt]
  // ========== G1^T: h1^T = W1^T @ feats^T, K=96 (xb direct, dbuf feats) =====
  #pragma unroll
  for (int nt = 0; nt < 4; nt++)
    #pragma unroll
    for (int bt = 0; bt < 4; bt++) acc[nt][bt] = (f32x4){0.f,0.f,0.f,0.f};

  {
    const unsigned short* PW1 = P + (((e*16 + wid*4)*3) << 9) + lane*8;
    s16x8 fB[2][4];
    #pragma unroll
    for (int bt = 0; bt < 4; bt++)
      fB[0][bt] = *(const s16x8*)(XB + (size_t)pA[bt]*96 + 8*lg);   // ks=0
    #pragma unroll
    for (int ks = 0; ks < 3; ks++) {
      const int cur = ks & 1, nxt = cur ^ 1;
      if (ks < 2) {
        #pragma unroll
        for (int bt = 0; bt < 4; bt++)
          fB[nxt][bt] = *(const s16x8*)(XB + (size_t)pA[bt]*96 + 32*(ks+1) + 8*lg);
      }
      #pragma unroll
      for (int nt = 0; nt < 4; nt++) {
        s16x8 a = *(const s16x8*)(PW1 + ((nt*3 + ks) << 9));
        #pragma unroll
        for (int bt = 0; bt < 4; bt++)
          acc[nt][bt] = __builtin_amdgcn_mfma_f32_16x16x32_bf16(a, fB[cur][bt], acc[nt][bt], 0,0,0);
      }
    }
  }

  // epilogue 1: bias+relu, pack, 8B write to sH (m-major, k-contig, XOR swz)
  #pragma unroll
  for (int nt = 0; nt < 4; nt++) {
    int ct = wid*4 + nt;
    float4 bv = *(const float4*)&b1[e*H_ + ct*16 + lg*4];
    #pragma unroll
    for (int bt = 0; bt < 4; bt++) {
      float v0 = fmaxf(acc[nt][bt][0] + bv.x, 0.f);
      float v1 = fmaxf(acc[nt][bt][1] + bv.y, 0.f);
      float v2 = fmaxf(acc[nt][bt][2] + bv.z, 0.f);
      float v3 = fmaxf(acc[nt][bt][3] + bv.w, 0.f);
      int m   = 16*bt + lr;
      int byt = (32*ct + 8*lg) ^ ((m & 7) << 4);
      uint2 pkd; pkd.x = pk2(v0, v1); pkd.y = pk2(v2, v3);
      *(uint2*)((char*)sH + m*512 + byt) = pkd;
    }
  }
  __syncthreads();

  // ========== G2^T: h2^T = W2^T @ h1^T, K=256 (dbuf weight A-frags) =========
  #pragma unroll
  for (int nt = 0; nt < 4; nt++)
    #pragma unroll
    for (int bt = 0; bt < 4; bt++) acc[nt][bt] = (f32x4){0.f,0.f,0.f,0.f};

  {
    const unsigned short* PW2 = P + W2P_OFF + (((e*16 + wid*4)*8) << 9) + lane*8;
    s16x8 awB[2][4];
    #pragma unroll
    for (int nt = 0; nt < 4; nt++)
      awB[0][nt] = *(const s16x8*)(PW2 + ((nt*8) << 9));            // ks=0
    #pragma unroll
    for (int ks = 0; ks < 8; ks++) {
      const int cur = ks & 1, nxt = cur ^ 1;
      if (ks < 7) {
        #pragma unroll
        for (int nt = 0; nt < 4; nt++)
          awB[nxt][nt] = *(const s16x8*)(PW2 + ((nt*8 + ks+1) << 9));
      }
      s16x8 bfr[4];
      #pragma unroll
      for (int bt = 0; bt < 4; bt++) {
        int m = 16*bt + lr;
        int byt = (64*ks + 16*lg) ^ ((m & 7) << 4);
        bfr[bt] = *(const s16x8*)((const char*)sH + m*512 + byt);
      }
      #pragma unroll
      for (int nt = 0; nt < 4; nt++) {
        #pragma unroll
        for (int bt = 0; bt < 4; bt++)
          acc[nt][bt] = __builtin_amdgcn_mfma_f32_16x16x32_bf16(awB[cur][nt], bfr[bt], acc[nt][bt], 0,0,0);
      }
    }
  }
  __syncthreads();   // all G2 reads of h1 complete

  // epilogue 2: bias+relu -> sH (h2)
  #pragma unroll
  for (int nt = 0; nt < 4; nt++) {
    int ct = wid*4 + nt;
    float4 bv = *(const float4*)&b2[e*H_ + ct*16 + lg*4];
    #pragma unroll
    for (int bt = 0; bt < 4; bt++) {
      float v0 = fmaxf(acc[nt][bt][0] + bv.x, 0.f);
      float v1 = fmaxf(acc[nt][bt][1] + bv.y, 0.f);
      float v2 = fmaxf(acc[nt][bt][2] + bv.z, 0.f);
      float v3 = fmaxf(acc[nt][bt][3] + bv.w, 0.f);
      int m   = 16*bt + lr;
      int byt = (32*ct + 8*lg) ^ ((m & 7) << 4);
      uint2 pkd; pkd.x = pk2(v0, v1); pkd.y = pk2(v2, v3);
      *(uint2*)((char*)sH + m*512 + byt) = pkd;
    }
  }
  __syncthreads();

  // ========== G3^T: out^T = W3^T @ h2^T (n3 padded to 16), wave w: bt=w =====
  f32x4 acc3 = (f32x4){0.f,0.f,0.f,0.f};
  #pragma unroll
  for (int ks = 0; ks < 8; ks++) {
    int m = 16*wid + lr;
    int byt = (64*ks + 16*lg) ^ ((m & 7) << 4);
    s16x8 bb = *(const s16x8*)((const char*)sH + m*512 + byt);
    s16x8 a  = *(const s16x8*)(P + W3P_OFF + ((e*8 + ks) << 9) + lane*8);
    acc3 = __builtin_amdgcn_mfma_f32_16x16x32_bf16(a, bb, acc3, 0,0,0);
  }

  // lane (lg=0, lr): rows n3=0..3 of point m=16*wid+lr  (pA[wid] is its index)
  if (lg == 0) {
    float wv = sWv[16*wid + lr];
    if (wv != 0.f) {
      int p = pA[wid];
      #pragma unroll
      for (int r = 0; r < 4; r++)
        atomicAdd(&out[(size_t)p*DOUT + r], wv * (acc3[r] + b3[e*DOUT + r]));
    }
  }
}

// ---------------- launcher --------------------------------------------------
extern "C" void kernel_launch(void* const* d_in, const int* in_sizes, int n_in,
                              void* d_out, int out_size, void* d_ws, size_t ws_size,
                              hipStream_t stream) {
  const float* x   = (const float*)d_in[0];
  const float* cen = (const float*)d_in[1];
  const float* W1  = (const float*)d_in[2];
  const float* b1  = (const float*)d_in[3];
  const float* W2  = (const float*)d_in[4];
  const float* b2  = (const float*)d_in[5];
  const float* W3  = (const float*)d_in[6];
  const float* b3  = (const float*)d_in[7];

  unsigned short* P     = (unsigned short*)d_ws;
  int*            cnts  = (int*)((char*)d_ws + CNT_OFF);
  unsigned short* lists = (unsigned short*)((char*)d_ws + LIST_OFF);
  unsigned short* XB    = (unsigned short*)((char*)d_ws + XB_OFF);
  float* out = (float*)d_out;

  (void)hipMemsetAsync(cnts, 0, 32, stream);
  (void)hipMemsetAsync(out, 0, (size_t)NPTS*DOUT*sizeof(float), stream);
  prep_pack<<<dim3((WSP_TOTAL + 255)/256), dim3(256), 0, stream>>>(W1, W2, W3, P);
  x_pack<<<dim3((NPTS*48 + 255)/256), dim3(256), 0, stream>>>(x, (unsigned*)XB);
  route_compact<<<dim3(NPTS/256), dim3(256), 0, stream>>>(x, cen, cnts, lists);
  expert_mlp<<<dim3(NPTS/64, E_), dim3(256), 0, stream>>>(x, cen, b1, b2, b3, P, XB,
                                                          cnts, lists, out);
}

// Round 8
// 107.033 us; speedup vs baseline: 3.2599x; 1.1527x over previous
//
#include <hip/hip_runtime.h>

// MegaNeRF fused MoE-MLP for MI355X (gfx950) — round 8: kill the spills.
// vs round 7: (1) launch_bounds(256,3) + no explicit dbuf -> live set fits,
// no scratch traffic (round 7: VGPR capped at 64, awB/bfr spilled, WRITE 92MB);
// (2) routing weights precomputed in route_compact (wlist f32) -> expert_mlp
// never touches x/cen. Layouts/epilogues identical to round-7 passing kernel.

typedef __attribute__((ext_vector_type(8))) short   s16x8;
typedef __attribute__((ext_vector_type(4))) float   f32x4;

#define NPTS  65536
#define E_    8
#define DIN   90
#define H_    256
#define DOUT  4

// packed weight layout: [e][ct][ks][lane][j] bf16, 512 elems per (e,ct,ks)
#define W1P_ELEMS (E_*16*3*512)   // K padded to 96 -> 3 ksteps
#define W2P_ELEMS (E_*16*8*512)   // K=256 -> 8 ksteps
#define W3P_ELEMS (E_*1*8*512)    // N padded 4->16, K=256
#define W2P_OFF   (W1P_ELEMS)
#define W3P_OFF   (W1P_ELEMS + W2P_ELEMS)
#define WSP_TOTAL (W1P_ELEMS + W2P_ELEMS + W3P_ELEMS)
#define WSP_BYTES (WSP_TOTAL*2)              // 1,507,328 B
#define CNT_OFF   WSP_BYTES                  // int[8]
#define LIST_OFF  (WSP_BYTES + 32)           // u16[E_*NPTS] = 1 MB
#define XB_OFF    (LIST_OFF + E_*NPTS*2)     // u16[NPTS*96] = 12.6 MB
#define WL_OFF    (XB_OFF + (size_t)NPTS*96*2)  // f32[E_*NPTS] = 2 MB
// total ws usage ~17.2 MB

__device__ __forceinline__ unsigned short f2bf(float f) {
  union { float f; unsigned u; } v; v.f = f;
  unsigned u = v.u;
  u += 0x7fffu + ((u >> 16) & 1u);   // round-to-nearest-even
  return (unsigned short)(u >> 16);
}
__device__ __forceinline__ unsigned pk2(float a, float b) {
  return (unsigned)f2bf(a) | ((unsigned)f2bf(b) << 16);
}

// ---------------- prep: pack W1/W2/W3 fp32 -> bf16 fragment layout ----------
__global__ void prep_pack(const float* __restrict__ W1,
                          const float* __restrict__ W2,
                          const float* __restrict__ W3,
                          unsigned short* __restrict__ P) {
  int idx = blockIdx.x * blockDim.x + threadIdx.x;
  if (idx >= WSP_TOTAL) return;
  float val;
  if (idx < W2P_OFF) {                       // W1: (e,90,256), K padded 96
    int f = idx;
    int j = f & 7, l = (f >> 3) & 63, t = f >> 9;
    int ks = t % 3; t /= 3;
    int ct = t & 15, e = t >> 4;
    int k = ks*32 + (l>>4)*8 + j;
    int n = ct*16 + (l & 15);
    val = (k < DIN) ? W1[((size_t)e*DIN + k)*H_ + n] : 0.f;
  } else if (idx < W3P_OFF) {                // W2: (e,256,256)
    int f = idx - W2P_OFF;
    int j = f & 7, l = (f >> 3) & 63, t = f >> 9;
    int ks = t & 7; t >>= 3;
    int ct = t & 15, e = t >> 4;
    int k = ks*32 + (l>>4)*8 + j;
    int n = ct*16 + (l & 15);
    val = W2[((size_t)e*H_ + k)*H_ + n];
  } else {                                   // W3: (e,256,4), N padded to 16
    int f = idx - W3P_OFF;
    int j = f & 7, l = (f >> 3) & 63, t = f >> 9;
    int ks = t & 7, e = t >> 3;
    int k = ks*32 + (l>>4)*8 + j;
    int n = l & 15;
    val = (n < DOUT) ? W3[((size_t)e*H_ + k)*DOUT + n] : 0.f;
  }
  P[idx] = f2bf(val);
}

// ---------------- prep: pack feats fp32 -> bf16 xb[N][96] -------------------
__global__ __launch_bounds__(256)
void x_pack(const float* __restrict__ x, unsigned* __restrict__ xb32) {
  int i = blockIdx.x * blockDim.x + threadIdx.x;   // one u32 (2 bf16) each
  if (i >= NPTS*48) return;
  int n = i / 48, c = i - n*48;                    // feat pair c -> dims 2c,2c+1
  const float* xr = x + (size_t)n*93 + 3;
  float v0 = (2*c   < DIN) ? xr[2*c]   : 0.f;
  float v1 = (2*c+1 < DIN) ? xr[2*c+1] : 0.f;
  xb32[(size_t)n*48 + c] = pk2(v0, v1);
}

// ---------------- routing + compaction (+ weight) into per-expert lists -----
__global__ __launch_bounds__(256)
void route_compact(const float* __restrict__ x,
                   const float* __restrict__ cen,
                   int* __restrict__ counts,
                   unsigned short* __restrict__ lists,
                   float* __restrict__ wlist) {
  const int tid = threadIdx.x;
  const int gid = blockIdx.x * 256 + tid;
  __shared__ int lcnt[E_], lbase[E_];
  if (tid < E_) lcnt[tid] = 0;
  __syncthreads();

  const float* xr = x + (size_t)gid*93;
  float px = xr[0], py = xr[1], pz = xr[2];
  float d[E_], dmin = 1e30f;
  #pragma unroll
  for (int e = 0; e < E_; e++) {
    float dx = px - cen[e*3+0], dy = py - cen[e*3+1], dz = pz - cen[e*3+2];
    d[e] = sqrtf(dx*dx + dy*dy + dz*dz);
    dmin = fminf(dmin, d[e]);
  }
  float inv[E_], s = 0.f;
  int act = 0;
  #pragma unroll
  for (int e = 0; e < E_; e++) {
    float iv = (d[e] > 2.0f*dmin) ? 0.f : 1.0f/(d[e] + 1e-8f);  // ref predicate
    inv[e] = iv; s += iv;
    if (iv > 0.f) act |= (1 << e);
  }
  float rs = 1.0f/s;
  int myoff[E_];
  #pragma unroll
  for (int e = 0; e < E_; e++)
    if ((act >> e) & 1) myoff[e] = atomicAdd(&lcnt[e], 1);
  __syncthreads();
  if (tid < E_) lbase[tid] = atomicAdd(&counts[tid], lcnt[tid]);
  __syncthreads();
  #pragma unroll
  for (int e = 0; e < E_; e++)
    if ((act >> e) & 1) {
      int slot = e*NPTS + lbase[e] + myoff[e];
      lists[slot] = (unsigned short)gid;
      wlist[slot] = inv[e]*rs;
    }
}

// ---------------- per-expert transposed MLP, 64 points per block ------------
__global__ __launch_bounds__(256, 3)
void expert_mlp(const float* __restrict__ b1,
                const float* __restrict__ b2,
                const float* __restrict__ b3,
                const unsigned short* __restrict__ P,
                const unsigned short* __restrict__ XB,
                const int* __restrict__ counts,
                const unsigned short* __restrict__ lists,
                const float* __restrict__ wlist,
                float* __restrict__ out) {
  const int e   = blockIdx.y;
  const int cnt = counts[e];
  const int t   = blockIdx.x;
  if (t*64 >= cnt) return;

  __shared__ __attribute__((aligned(16))) unsigned short sH[64*256];  // 32KB

  const int tid  = threadIdx.x;
  const int wid  = tid >> 6;
  const int lane = tid & 63;
  const int lg   = lane >> 4;
  const int lr   = lane & 15;

  // ---- per-bt point indices (lane lr owns point 16*bt+lr)
  int pA[4];
  #pragma unroll
  for (int bt = 0; bt < 4; bt++) {
    int slot = t*64 + 16*bt + lr;
    pA[bt] = (slot < cnt) ? (int)lists[e*NPTS + slot] : 0;
  }

  f32x4 acc[4][4];   // [nt][bt]
  // ========== G1^T: h1^T = W1^T @ feats^T, K=96 (XB direct) =================
  #pragma unroll
  for (int nt = 0; nt < 4; nt++)
    #pragma unroll
    for (int bt = 0; bt < 4; bt++) acc[nt][bt] = (f32x4){0.f,0.f,0.f,0.f};

  {
    const unsigned short* PW1 = P + (((e*16 + wid*4)*3) << 9) + lane*8;
    #pragma unroll
    for (int ks = 0; ks < 3; ks++) {
      s16x8 bfr[4];
      #pragma unroll
      for (int bt = 0; bt < 4; bt++)
        bfr[bt] = *(const s16x8*)(XB + (size_t)pA[bt]*96 + 32*ks + 8*lg);
      #pragma unroll
      for (int nt = 0; nt < 4; nt++) {
        s16x8 a = *(const s16x8*)(PW1 + ((nt*3 + ks) << 9));
        #pragma unroll
        for (int bt = 0; bt < 4; bt++)
          acc[nt][bt] = __builtin_amdgcn_mfma_f32_16x16x32_bf16(a, bfr[bt], acc[nt][bt], 0,0,0);
      }
    }
  }

  // epilogue 1: bias+relu, pack, 8B write to sH (m-major, k-contig, XOR swz)
  #pragma unroll
  for (int nt = 0; nt < 4; nt++) {
    int ct = wid*4 + nt;
    float4 bv = *(const float4*)&b1[e*H_ + ct*16 + lg*4];
    #pragma unroll
    for (int bt = 0; bt < 4; bt++) {
      float v0 = fmaxf(acc[nt][bt][0] + bv.x, 0.f);
      float v1 = fmaxf(acc[nt][bt][1] + bv.y, 0.f);
      float v2 = fmaxf(acc[nt][bt][2] + bv.z, 0.f);
      float v3 = fmaxf(acc[nt][bt][3] + bv.w, 0.f);
      int m   = 16*bt + lr;
      int byt = (32*ct + 8*lg) ^ ((m & 7) << 4);
      uint2 pkd; pkd.x = pk2(v0, v1); pkd.y = pk2(v2, v3);
      *(uint2*)((char*)sH + m*512 + byt) = pkd;
    }
  }
  __syncthreads();

  // ========== G2^T: h2^T = W2^T @ h1^T, K=256 ==========
  #pragma unroll
  for (int nt = 0; nt < 4; nt++)
    #pragma unroll
    for (int bt = 0; bt < 4; bt++) acc[nt][bt] = (f32x4){0.f,0.f,0.f,0.f};

  {
    const unsigned short* PW2 = P + W2P_OFF + (((e*16 + wid*4)*8) << 9) + lane*8;
    #pragma unroll
    for (int ks = 0; ks < 8; ks++) {
      s16x8 bfr[4];
      #pragma unroll
      for (int bt = 0; bt < 4; bt++) {
        int m = 16*bt + lr;
        int byt = (64*ks + 16*lg) ^ ((m & 7) << 4);
        bfr[bt] = *(const s16x8*)((const char*)sH + m*512 + byt);
      }
      #pragma unroll
      for (int nt = 0; nt < 4; nt++) {
        s16x8 a = *(const s16x8*)(PW2 + ((nt*8 + ks) << 9));
        #pragma unroll
        for (int bt = 0; bt < 4; bt++)
          acc[nt][bt] = __builtin_amdgcn_mfma_f32_16x16x32_bf16(a, bfr[bt], acc[nt][bt], 0,0,0);
      }
    }
  }
  __syncthreads();   // all G2 reads of h1 complete

  // epilogue 2: bias+relu -> sH (h2)
  #pragma unroll
  for (int nt = 0; nt < 4; nt++) {
    int ct = wid*4 + nt;
    float4 bv = *(const float4*)&b2[e*H_ + ct*16 + lg*4];
    #pragma unroll
    for (int bt = 0; bt < 4; bt++) {
      float v0 = fmaxf(acc[nt][bt][0] + bv.x, 0.f);
      float v1 = fmaxf(acc[nt][bt][1] + bv.y, 0.f);
      float v2 = fmaxf(acc[nt][bt][2] + bv.z, 0.f);
      float v3 = fmaxf(acc[nt][bt][3] + bv.w, 0.f);
      int m   = 16*bt + lr;
      int byt = (32*ct + 8*lg) ^ ((m & 7) << 4);
      uint2 pkd; pkd.x = pk2(v0, v1); pkd.y = pk2(v2, v3);
      *(uint2*)((char*)sH + m*512 + byt) = pkd;
    }
  }
  __syncthreads();

  // ========== G3^T: out^T = W3^T @ h2^T (n3 padded to 16), wave w: bt=w =====
  f32x4 acc3 = (f32x4){0.f,0.f,0.f,0.f};
  #pragma unroll
  for (int ks = 0; ks < 8; ks++) {
    int m = 16*wid + lr;
    int byt = (64*ks + 16*lg) ^ ((m & 7) << 4);
    s16x8 bb = *(const s16x8*)((const char*)sH + m*512 + byt);
    s16x8 a  = *(const s16x8*)(P + W3P_OFF + ((e*8 + ks) << 9) + lane*8);
    acc3 = __builtin_amdgcn_mfma_f32_16x16x32_bf16(a, bb, acc3, 0,0,0);
  }

  // lane (lg=0, lr): rows n3=0..3 of point m=16*wid+lr  (pA[wid] is its index)
  if (lg == 0) {
    int slot = t*64 + 16*wid + lr;
    float wv = (slot < cnt) ? wlist[e*NPTS + slot] : 0.f;
    if (wv != 0.f) {
      int p = pA[wid];
      #pragma unroll
      for (int r = 0; r < 4; r++)
        atomicAdd(&out[(size_t)p*DOUT + r], wv * (acc3[r] + b3[e*DOUT + r]));
    }
  }
}

// ---------------- launcher --------------------------------------------------
extern "C" void kernel_launch(void* const* d_in, const int* in_sizes, int n_in,
                              void* d_out, int out_size, void* d_ws, size_t ws_size,
                              hipStream_t stream) {
  const float* x   = (const float*)d_in[0];
  const float* cen = (const float*)d_in[1];
  const float* W1  = (const float*)d_in[2];
  const float* b1  = (const float*)d_in[3];
  const float* W2  = (const float*)d_in[4];
  const float* b2  = (const float*)d_in[5];
  const float* W3  = (const float*)d_in[6];
  const float* b3  = (const float*)d_in[7];

  unsigned short* P     = (unsigned short*)d_ws;
  int*            cnts  = (int*)((char*)d_ws + CNT_OFF);
  unsigned short* lists = (unsigned short*)((char*)d_ws + LIST_OFF);
  unsigned short* XB    = (unsigned short*)((char*)d_ws + XB_OFF);
  float*          WL    = (float*)((char*)d_ws + WL_OFF);
  float* out = (float*)d_out;

  (void)hipMemsetAsync(cnts, 0, 32, stream);
  (void)hipMemsetAsync(out, 0, (size_t)NPTS*DOUT*sizeof(float), stream);
  prep_pack<<<dim3((WSP_TOTAL + 255)/256), dim3(256), 0, stream>>>(W1, W2, W3, P);
  x_pack<<<dim3((NPTS*48 + 255)/256), dim3(256), 0, stream>>>(x, (unsigned*)XB);
  route_compact<<<dim3(NPTS/256), dim3(256), 0, stream>>>(x, cen, cnts, lists, WL);
  expert_mlp<<<dim3(NPTS/64, E_), dim3(256), 0, stream>>>(b1, b2, b3, P, XB,
                                                          cnts, lists, WL, out);
}